// Round 2
// baseline (435.357 us; speedup 1.0000x reference)
//
#include <hip/hip_runtime.h>

#define N_NODES 100000
#define N_EDGES 1600000
#define F 128
#define H 16
#define C 40

// ---------------- zero-fill (d_ws is poisoned 0xAA before every launch) -----
__global__ __launch_bounds__(256) void k_zero(float* __restrict__ p, int n) {
  int t = blockIdx.x * 256 + threadIdx.x;
  if (t < n) p[t] = 0.0f;
}

// ---------------- layer-1 projection: xn1 = x@Wn1, y1 = x@Ws1 + b1 ----------
// 16 nodes per block, 16 threads per node (block = 256).
__global__ __launch_bounds__(256) void k_proj1(
    const float* __restrict__ x, const float* __restrict__ wn,
    const float* __restrict__ wsf, const float* __restrict__ b,
    float* __restrict__ xn1, float* __restrict__ y1) {
  __shared__ float wn_s[F * H];
  __shared__ float ws_s[F * H];
  __shared__ float xs[16 * F];
  const int tid = threadIdx.x;
  for (int i = tid; i < F * H; i += 256) {
    wn_s[i] = wn[i];
    ws_s[i] = wsf[i];
  }
  const int node0 = blockIdx.x * 16;
  for (int i = tid; i < 16 * F; i += 256) {
    int n = node0 + (i >> 7);
    xs[i] = (n < N_NODES) ? x[(size_t)n * F + (i & (F - 1))] : 0.f;
  }
  __syncthreads();
  const int nl = tid >> 4;  // local node 0..15
  const int j = tid & 15;   // output column 0..15
  float an = 0.f, as = 0.f;
#pragma unroll 8
  for (int k = 0; k < F; ++k) {
    float xv = xs[nl * F + k];
    an += xv * wn_s[k * H + j];
    as += xv * ws_s[k * H + j];
  }
  const int n = node0 + nl;
  if (n < N_NODES) {
    xn1[n * H + j] = an;
    y1[n * H + j] = as + b[j];
  }
}

// ---------------- degree count ----------------------------------------------
__global__ __launch_bounds__(256) void k_deg(const int* __restrict__ dst,
                                             float* __restrict__ deg) {
  int t = blockIdx.x * 256 + threadIdx.x;
  if (t < N_EDGES) atomicAdd(&deg[dst[t]], 1.0f);
}

// ---------------- scatter-add 16-float rows: agg[dst] += v[src] -------------
__global__ __launch_bounds__(256) void k_scatter(const float* __restrict__ v,
                                                 const int* __restrict__ src,
                                                 const int* __restrict__ dst,
                                                 float* __restrict__ agg) {
  int t = blockIdx.x * 256 + threadIdx.x;
  if (t >= N_EDGES * H) return;
  int e = t >> 4;
  int j = t & 15;
  int s = src[e];
  int d = dst[e];
  atomicAdd(&agg[d * H + j], v[s * H + j]);
}

// ---------------- deg -> 1/max(deg,1) ---------------------------------------
__global__ __launch_bounds__(256) void k_rdeg(float* __restrict__ deg) {
  int t = blockIdx.x * 256 + threadIdx.x;
  if (t < N_NODES) deg[t] = 1.0f / fmaxf(deg[t], 1.0f);
}

// ---------------- h = relu(y1 + agg1 * rdeg) (in place on y1) ---------------
__global__ __launch_bounds__(256) void k_hidden(float* __restrict__ y1h,
                                                const float* __restrict__ agg1,
                                                const float* __restrict__ rdeg) {
  int t = blockIdx.x * 256 + threadIdx.x;
  if (t < N_NODES * H) {
    int n = t >> 4;
    float v = y1h[t] + agg1[t] * rdeg[n];
    y1h[t] = fmaxf(v, 0.f);
  }
}

// ---------------- layer-2: out = h@Ws2 + (agg2*rdeg)@Wn2 + b2 ---------------
// 8 nodes per block, 40 threads per node (block = 320 = 5 waves).
__global__ __launch_bounds__(320) void k_out(
    const float* __restrict__ h, const float* __restrict__ agg2,
    const float* __restrict__ rdeg, const float* __restrict__ wn,
    const float* __restrict__ wsf, const float* __restrict__ b,
    float* __restrict__ out) {
  __shared__ float wn_s[H * C];
  __shared__ float ws_s[H * C];
  __shared__ float b_s[C];
  const int tid = threadIdx.x;
  for (int i = tid; i < H * C; i += 320) {
    wn_s[i] = wn[i];
    ws_s[i] = wsf[i];
  }
  if (tid < C) b_s[tid] = b[tid];
  __syncthreads();
  const int nl = tid / C;
  const int c = tid % C;
  const int n = blockIdx.x * 8 + nl;
  if (n >= N_NODES) return;
  const float rd = rdeg[n];
  float acc = b_s[c];
#pragma unroll
  for (int j = 0; j < H; ++j) {
    float hv = h[n * H + j];
    float mv = agg2[n * H + j] * rd;
    acc += hv * ws_s[j * C + c] + mv * wn_s[j * C + c];
  }
  out[n * C + c] = acc;
}

extern "C" void kernel_launch(void* const* d_in, const int* in_sizes, int n_in,
                              void* d_out, int out_size, void* d_ws,
                              size_t ws_size, hipStream_t stream) {
  const float* x = (const float*)d_in[0];
  const int* src = (const int*)d_in[1];
  const int* dst = (const int*)d_in[2];
  const float* wn1 = (const float*)d_in[3];
  const float* ws1 = (const float*)d_in[4];
  const float* b1 = (const float*)d_in[5];
  const float* wn2 = (const float*)d_in[6];
  const float* ws2 = (const float*)d_in[7];
  const float* b2 = (const float*)d_in[8];
  float* out = (float*)d_out;

  const int NH = N_NODES * H;  // 1.6M floats

  // xn1 is consumed (by the first k_scatter) before k_out writes d_out,
  // so it can live in d_out's first NH floats (d_out has 4M floats).
  float* xn1 = out;

  // workspace (floats): deg[102400] | y1h[NH] | agg[NH]  -> 13.2 MB total.
  // agg serves as agg1, then is re-zeroed and reused as agg2.
  float* ws = (float*)d_ws;
  float* deg = ws;
  float* y1h = ws + 102400;
  float* agg = y1h + NH;

  k_zero<<<(N_NODES + 255) / 256, 256, 0, stream>>>(deg, N_NODES);
  k_zero<<<(NH + 255) / 256, 256, 0, stream>>>(agg, NH);

  k_proj1<<<(N_NODES + 15) / 16, 256, 0, stream>>>(x, wn1, ws1, b1, xn1, y1h);
  k_deg<<<(N_EDGES + 255) / 256, 256, 0, stream>>>(dst, deg);
  k_scatter<<<(N_EDGES * H + 255) / 256, 256, 0, stream>>>(xn1, src, dst, agg);
  k_rdeg<<<(N_NODES + 255) / 256, 256, 0, stream>>>(deg);
  k_hidden<<<(NH + 255) / 256, 256, 0, stream>>>(y1h, agg, deg);

  // reuse agg as agg2
  k_zero<<<(NH + 255) / 256, 256, 0, stream>>>(agg, NH);
  k_scatter<<<(N_EDGES * H + 255) / 256, 256, 0, stream>>>(y1h, src, dst, agg);
  k_out<<<(N_NODES + 7) / 8, 320, 0, stream>>>(y1h, agg, deg, wn2, ws2, b2,
                                               out);
}

// Round 3
// 404.588 us; speedup vs baseline: 1.0761x; 1.0761x over previous
//
#include <hip/hip_runtime.h>

#define N_NODES 100000
#define N_EDGES 1600000
#define F 128
#define H 16
#define C 40
#define NH (N_NODES * H)

// ---------------- zero-fill (ws is poisoned 0xAA before every launch) -------
__global__ __launch_bounds__(256) void k_zero(float* __restrict__ p, int n) {
  int t = blockIdx.x * 256 + threadIdx.x;
  if (t < n) p[t] = 0.0f;
}

// ---------------- layer-1 projection: xn1 = x@Wn1, y1 = x@Ws1 + b1 ----------
// 64 nodes per block, 256 threads = 4 waves. Wave w computes 8 output cols
// (w0,w1 -> Wn cols 0-7/8-15 ; w2,w3 -> Ws cols 0-7/8-15) for all 64 nodes.
// Weight indices are wave-uniform -> scalar loads via constant cache; the only
// LDS traffic is the x broadcast (pad 129 -> 2-way, free).
__global__ __launch_bounds__(256) void k_proj1(
    const float* __restrict__ x, const float* __restrict__ wn,
    const float* __restrict__ wsf, const float* __restrict__ b,
    float* __restrict__ xn1, float* __restrict__ y1) {
  __shared__ float xs[64 * 129];
  const int tid = threadIdx.x;
  const int node0 = blockIdx.x * 64;
  // stage x tile: 64 rows x 128 floats, float4 global loads
  for (int i = tid; i < 64 * 32; i += 256) {
    int r = i >> 5, cv = i & 31;
    int n = node0 + r;
    float4 v = make_float4(0.f, 0.f, 0.f, 0.f);
    if (n < N_NODES) v = ((const float4*)x)[(size_t)n * 32 + cv];
    float* dp = &xs[r * 129 + cv * 4];
    dp[0] = v.x; dp[1] = v.y; dp[2] = v.z; dp[3] = v.w;
  }
  __syncthreads();

  const int wave = __builtin_amdgcn_readfirstlane(tid >> 6);  // 0..3, uniform
  const int lane = tid & 63;                                  // node in block
  const int n = node0 + lane;
  const float* wmat = (wave < 2) ? wn : wsf;  // [F][H] row-major
  const int c0 = (wave & 1) * 8;

  float acc[8] = {0.f, 0.f, 0.f, 0.f, 0.f, 0.f, 0.f, 0.f};
  const float* xrow = &xs[lane * 129];
#pragma unroll 8
  for (int k = 0; k < F; ++k) {
    float xv = xrow[k];
    const float* wr = wmat + k * H + c0;  // uniform -> s_load
#pragma unroll
    for (int j = 0; j < 8; ++j) acc[j] += xv * wr[j];
  }
  if (n < N_NODES) {
    if (wave < 2) {
#pragma unroll
      for (int j = 0; j < 8; ++j) xn1[n * H + c0 + j] = acc[j];
    } else {
#pragma unroll
      for (int j = 0; j < 8; ++j) y1[n * H + c0 + j] = acc[j] + b[c0 + j];
    }
  }
}

// ---------------- scatter-add + degree (layer 1) ----------------------------
__global__ __launch_bounds__(256) void k_scatter_deg(
    const float* __restrict__ v, const int* __restrict__ src,
    const int* __restrict__ dst, float* __restrict__ agg,
    float* __restrict__ deg) {
  int t = blockIdx.x * 256 + threadIdx.x;
  if (t >= N_EDGES * H) return;
  int e = t >> 4;
  int j = t & 15;
  int s = src[e];
  int d = dst[e];
  atomicAdd(&agg[d * H + j], v[s * H + j]);
  if (j == 0) atomicAdd(&deg[d], 1.0f);
}

// ---------------- scatter-add (layer 2) -------------------------------------
__global__ __launch_bounds__(256) void k_scatter(const float* __restrict__ v,
                                                 const int* __restrict__ src,
                                                 const int* __restrict__ dst,
                                                 float* __restrict__ agg) {
  int t = blockIdx.x * 256 + threadIdx.x;
  if (t >= N_EDGES * H) return;
  int e = t >> 4;
  int j = t & 15;
  int s = src[e];
  int d = dst[e];
  atomicAdd(&agg[d * H + j], v[s * H + j]);
}

// ------- h = relu(y1 + agg1/max(deg,1)) in place; re-zero agg for layer 2 ---
__global__ __launch_bounds__(256) void k_hidden(float* __restrict__ y1h,
                                                float* __restrict__ agg,
                                                const float* __restrict__ deg) {
  int t = blockIdx.x * 256 + threadIdx.x;
  if (t < NH) {
    int n = t >> 4;
    float r = 1.0f / fmaxf(deg[n], 1.0f);
    float v = y1h[t] + agg[t] * r;
    y1h[t] = fmaxf(v, 0.f);
    agg[t] = 0.f;
  }
}

// ---------------- layer-2: out = h@Ws2 + (agg2/max(deg,1))@Wn2 + b2 ---------
// 8 nodes per block, 40 threads per node (block = 320 = 5 waves).
__global__ __launch_bounds__(320) void k_out(
    const float* __restrict__ h, const float* __restrict__ agg2,
    const float* __restrict__ deg, const float* __restrict__ wn,
    const float* __restrict__ wsf, const float* __restrict__ b,
    float* __restrict__ out) {
  __shared__ float wn_s[H * C];
  __shared__ float ws_s[H * C];
  __shared__ float b_s[C];
  const int tid = threadIdx.x;
  for (int i = tid; i < H * C; i += 320) {
    wn_s[i] = wn[i];
    ws_s[i] = wsf[i];
  }
  if (tid < C) b_s[tid] = b[tid];
  __syncthreads();
  const int nl = tid / C;
  const int c = tid % C;
  const int n = blockIdx.x * 8 + nl;
  if (n >= N_NODES) return;
  const float rd = 1.0f / fmaxf(deg[n], 1.0f);
  float acc = b_s[c];
#pragma unroll
  for (int j = 0; j < H; ++j) {
    float hv = h[n * H + j];
    float mv = agg2[n * H + j] * rd;
    acc += hv * ws_s[j * C + c] + mv * wn_s[j * C + c];
  }
  out[n * C + c] = acc;
}

extern "C" void kernel_launch(void* const* d_in, const int* in_sizes, int n_in,
                              void* d_out, int out_size, void* d_ws,
                              size_t ws_size, hipStream_t stream) {
  const float* x = (const float*)d_in[0];
  const int* src = (const int*)d_in[1];
  const int* dst = (const int*)d_in[2];
  const float* wn1 = (const float*)d_in[3];
  const float* ws1 = (const float*)d_in[4];
  const float* b1 = (const float*)d_in[5];
  const float* wn2 = (const float*)d_in[6];
  const float* ws2 = (const float*)d_in[7];
  const float* b2 = (const float*)d_in[8];
  float* out = (float*)d_out;

  // xn1 lives in d_out's first NH floats (consumed before k_out writes d_out).
  float* xn1 = out;

  // ws layout (floats): deg[102400] | agg[NH] | y1h[NH] -> 13.2 MB.
  // deg+agg are contiguous -> one zero-fill covers both.
  float* wsp = (float*)d_ws;
  float* deg = wsp;
  float* agg = wsp + 102400;
  float* y1h = agg + NH;

  const int nz = 102400 + NH;
  k_zero<<<(nz + 255) / 256, 256, 0, stream>>>(deg, nz);
  k_proj1<<<(N_NODES + 63) / 64, 256, 0, stream>>>(x, wn1, ws1, b1, xn1, y1h);
  k_scatter_deg<<<(N_EDGES * H + 255) / 256, 256, 0, stream>>>(xn1, src, dst,
                                                               agg, deg);
  k_hidden<<<(NH + 255) / 256, 256, 0, stream>>>(y1h, agg, deg);
  k_scatter<<<(N_EDGES * H + 255) / 256, 256, 0, stream>>>(y1h, src, dst, agg);
  k_out<<<(N_NODES + 7) / 8, 320, 0, stream>>>(y1h, agg, deg, wn2, ws2, b2,
                                               out);
}